// Round 1
// baseline (18415.948 us; speedup 1.0000x reference)
//
#include <hip/hip_runtime.h>

// PoseConvLSTM: T=128, layer1: Cin=3+32 -> 4*32 gates, layer2: Cin=32+64 -> 4*64 gates,
// 64x64 spatial, 3x3 SAME conv, then FC [6, 64*64*64] over ys2.
//
// d_out layout (floats): pose[128*6]=768 | h1[32*4096] | c1[32*4096] | h2[64*4096] | c2[64*4096]
// ws layout   (floats): h1_pong[131072] | h2_pong[262144] | w1packed[40320] | w2packed[221184]

__device__ __forceinline__ float sigm(float x) { return 1.0f / (1.0f + __expf(-x)); }

// ---- init: pose = fc_b broadcast; pack weights into per-block-group contiguous layout ----
__global__ __launch_bounds__(256) void init_pack(const float* __restrict__ w1,
                                                 const float* __restrict__ w2,
                                                 const float* __restrict__ fcb,
                                                 float* __restrict__ pose,
                                                 float* __restrict__ w1p,
                                                 float* __restrict__ w2p) {
  int idx = blockIdx.x * 256 + threadIdx.x;
  if (idx < 768) pose[idx] = fcb[idx % 6];
  if (idx < 40320) {  // w1p[group(16)][c(35)][h(2)][G(4)][tap(9)], hb=group*2
    int group = idx / 2520;
    int r = idx % 2520;
    int c = r / 72;
    int r2 = r % 72;
    int h = r2 / 36;
    int G = (r2 % 36) / 9;
    int tap = r2 % 9;
    w1p[idx] = w1[((G * 32 + group * 2 + h) * 35 + c) * 9 + tap];
  }
  if (idx < 221184) {  // w2p[group(16)][cg(96)][h(4)][G(4)][tap(9)], hb=group*4
    int group = idx / 13824;
    int r = idx % 13824;
    int cg = r / 144;
    int r2 = r % 144;
    int h = r2 / 36;
    int G = (r2 % 36) / 9;
    int tap = r2 % 9;
    w2p[idx] = w2[((G * 64 + group * 4 + h) * 96 + cg) * 9 + tap];
  }
}

// ---- layer 1, one timestep ----
// grid 256 = 16 tiles (4x4 of 16x16 pixels) x 16 groups (2 hidden ch each)
__global__ __launch_bounds__(256) void layer1_step(const float* __restrict__ x,      // [3,64,64]
                                                   const float* __restrict__ hprev,  // [32,64,64]
                                                   float* __restrict__ c1,           // in-place
                                                   const float* __restrict__ wp,     // packed
                                                   const float* __restrict__ b1,     // [128]
                                                   float* __restrict__ hnext) {
  __shared__ float sm[35 * 324];  // 35 ch x 18x18 halo tile (45.4 KB)
  const int tid = threadIdx.x;
  const int tile = blockIdx.x & 15;
  const int group = blockIdx.x >> 4;
  const int ty0 = (tile >> 2) * 16, tx0 = (tile & 3) * 16;

  for (int i = tid; i < 35 * 324; i += 256) {
    int c = i / 324;
    int r = i % 324;
    int yy = r / 18, xx = r % 18;
    int gy = ty0 + yy - 1, gx = tx0 + xx - 1;
    float v = 0.f;
    if ((unsigned)gy < 64u && (unsigned)gx < 64u) {
      int off = gy * 64 + gx;
      v = (c < 3) ? x[c * 4096 + off] : hprev[(c - 3) * 4096 + off];
    }
    sm[i] = v;
  }
  __syncthreads();

  const int py = tid >> 4, px = tid & 15;
  const int hb = group * 2;
  float acc[8];
#pragma unroll
  for (int h = 0; h < 2; ++h)
#pragma unroll
    for (int G = 0; G < 4; ++G) acc[h * 4 + G] = b1[G * 32 + hb + h];

  const float* wg = wp + group * 2520;
  for (int c = 0; c < 35; ++c) {
    float xv[9];
    const float* s = sm + c * 324 + py * 18 + px;
#pragma unroll
    for (int dy = 0; dy < 3; ++dy)
#pragma unroll
      for (int dx = 0; dx < 3; ++dx) xv[dy * 3 + dx] = s[dy * 18 + dx];
    const float* wc = wg + c * 72;
#pragma unroll
    for (int q = 0; q < 8; ++q)
#pragma unroll
      for (int tap = 0; tap < 9; ++tap) acc[q] += xv[tap] * wc[q * 9 + tap];
  }

  const int pix = (ty0 + py) * 64 + tx0 + px;
#pragma unroll
  for (int h = 0; h < 2; ++h) {
    float zi = acc[h * 4 + 0], zf = acc[h * 4 + 1], zo = acc[h * 4 + 2], zg = acc[h * 4 + 3];
    int idx = (hb + h) * 4096 + pix;
    float cold = c1[idx];
    float cn = sigm(zf) * cold + sigm(zi) * tanhf(zg);
    float hn = sigm(zo) * tanhf(cn);
    c1[idx] = cn;
    hnext[idx] = hn;
  }
}

// ---- layer 2, one timestep (+ fused FC partial) ----
// grid 256 = 16 tiles x 16 groups (4 hidden ch each)
__global__ __launch_bounds__(256) void layer2_step(const float* __restrict__ h1,     // [32,64,64]
                                                   const float* __restrict__ hprev,  // [64,64,64]
                                                   float* __restrict__ c2,           // in-place
                                                   const float* __restrict__ wp,
                                                   const float* __restrict__ b2,  // [256]
                                                   float* __restrict__ hnext,
                                                   const float* __restrict__ fcw,  // [6][262144]
                                                   float* __restrict__ pose_t) {   // [6]
  __shared__ float sm[32 * 324];  // one 32-channel chunk (41.5 KB)
  __shared__ float red[4][6];
  const int tid = threadIdx.x;
  const int tile = blockIdx.x & 15;
  const int group = blockIdx.x >> 4;
  const int ty0 = (tile >> 2) * 16, tx0 = (tile & 3) * 16;
  const int py = tid >> 4, px = tid & 15;
  const int hb = group * 4;

  float acc[16];
#pragma unroll
  for (int h = 0; h < 4; ++h)
#pragma unroll
    for (int G = 0; G < 4; ++G) acc[h * 4 + G] = b2[G * 64 + hb + h];

  const float* wg = wp + group * 13824;

  for (int chunk = 0; chunk < 3; ++chunk) {
    if (chunk) __syncthreads();
    for (int i = tid; i < 32 * 324; i += 256) {
      int c = i / 324;
      int r = i % 324;
      int yy = r / 18, xx = r % 18;
      int gy = ty0 + yy - 1, gx = tx0 + xx - 1;
      int cg = chunk * 32 + c;
      float v = 0.f;
      if ((unsigned)gy < 64u && (unsigned)gx < 64u) {
        int off = gy * 64 + gx;
        v = (cg < 32) ? h1[cg * 4096 + off] : hprev[(cg - 32) * 4096 + off];
      }
      sm[i] = v;
    }
    __syncthreads();
    for (int c = 0; c < 32; ++c) {
      float xv[9];
      const float* s = sm + c * 324 + py * 18 + px;
#pragma unroll
      for (int dy = 0; dy < 3; ++dy)
#pragma unroll
        for (int dx = 0; dx < 3; ++dx) xv[dy * 3 + dx] = s[dy * 18 + dx];
      const float* wc = wg + (chunk * 32 + c) * 144;
#pragma unroll
      for (int q = 0; q < 16; ++q)
#pragma unroll
        for (int tap = 0; tap < 9; ++tap) acc[q] += xv[tap] * wc[q * 9 + tap];
    }
  }

  const int pix = (ty0 + py) * 64 + tx0 + px;
  float p[6] = {0, 0, 0, 0, 0, 0};
#pragma unroll
  for (int h = 0; h < 4; ++h) {
    float zi = acc[h * 4 + 0], zf = acc[h * 4 + 1], zo = acc[h * 4 + 2], zg = acc[h * 4 + 3];
    int idx = (hb + h) * 4096 + pix;
    float cold = c2[idx];
    float cn = sigm(zf) * cold + sigm(zi) * tanhf(zg);
    float hn = sigm(zo) * tanhf(cn);
    c2[idx] = cn;
    hnext[idx] = hn;
    const float* fw = fcw + idx;
#pragma unroll
    for (int j = 0; j < 6; ++j) p[j] += hn * fw[j * 262144];
  }

  // block-reduce the 6 FC partials, one atomicAdd set per block
#pragma unroll
  for (int j = 0; j < 6; ++j) {
#pragma unroll
    for (int off = 32; off > 0; off >>= 1) p[j] += __shfl_xor(p[j], off, 64);
  }
  int lane = tid & 63, wid = tid >> 6;
  if (lane == 0) {
#pragma unroll
    for (int j = 0; j < 6; ++j) red[wid][j] = p[j];
  }
  __syncthreads();
  if (tid < 6) {
    float s = red[0][tid] + red[1][tid] + red[2][tid] + red[3][tid];
    atomicAdd(pose_t + tid, s);
  }
}

extern "C" void kernel_launch(void* const* d_in, const int* in_sizes, int n_in, void* d_out,
                              int out_size, void* d_ws, size_t ws_size, hipStream_t stream) {
  const float* input = (const float*)d_in[0];  // [128,3,64,64]
  const float* w1 = (const float*)d_in[1];     // [128,35,3,3]
  const float* b1 = (const float*)d_in[2];     // [128]
  const float* w2 = (const float*)d_in[3];     // [256,96,3,3]
  const float* b2 = (const float*)d_in[4];     // [256]
  const float* fcw = (const float*)d_in[5];    // [6,262144]
  const float* fcb = (const float*)d_in[6];    // [6]

  float* out = (float*)d_out;
  float* pose = out;                          // 768
  float* h1o = out + 768;                     // 131072
  float* c1o = out + 768 + 131072;            // 131072
  float* h2o = out + 768 + 2 * 131072;        // 262144
  float* c2o = out + 768 + 2 * 131072 + 262144;  // 262144

  float* ws = (float*)d_ws;
  float* h1b = ws;
  float* h2b = ws + 131072;
  float* w1p = ws + 131072 + 262144;
  float* w2p = w1p + 40320;

  // zero all state regions of d_out (they double as the t=0 h/c inputs and
  // the in-place c buffers); pose gets fc_b in init_pack.
  hipMemsetAsync(out + 768, 0, (size_t)(2 * 131072 + 2 * 262144) * sizeof(float), stream);
  init_pack<<<864, 256, 0, stream>>>(w1, w2, fcb, pose, w1p, w2p);

  for (int t = 0; t < 128; ++t) {
    // parity chosen so step t=127 writes h into d_out regions
    const float* h1p = (t & 1) ? h1b : h1o;
    float* h1n = (t & 1) ? h1o : h1b;
    layer1_step<<<256, 256, 0, stream>>>(input + (size_t)t * 3 * 4096, h1p, c1o, w1p, b1, h1n);
    const float* h2p = (t & 1) ? h2b : h2o;
    float* h2n = (t & 1) ? h2o : h2b;
    layer2_step<<<256, 256, 0, stream>>>(h1n, h2p, c2o, w2p, b2, h2n, fcw, pose + t * 6);
  }
}

// Round 2
// 6477.825 us; speedup vs baseline: 2.8429x; 2.8429x over previous
//
#include <hip/hip_runtime.h>

typedef _Float16 f16;
typedef _Float16 f16x8 __attribute__((ext_vector_type(8)));
typedef float f32x4 __attribute__((ext_vector_type(4)));
typedef unsigned short ushort_t;

// ---------------------------------------------------------------------------
// PoseConvLSTM via implicit-GEMM MFMA (split-fp16 hi/lo, 3-MFMA per product).
//
// State buffers (ws, ushort f16 bits), padded-transposed layout [66][66][C]:
//   in1[parity]: C=48: c0-2 = x[t], c3-34 = h1prev, c35-47 = 0
//   in2[parity]: C=96: c0-31 = h1[t], c32-95 = h2prev
// Weights packed at init into MFMA A-fragment order (hi/lo f16).
//
// d_out (floats): pose[768] | h1[131072] | c1[131072] | h2[262144] | c2[262144]
// ---------------------------------------------------------------------------

#define IN1SZ 209088   // 66*66*48
#define IN2SZ 418176   // 66*66*96
#define WP1OFF 2509056            // ushort offset of wp1 (after 4*IN1SZ + 4*IN2SZ)
#define WP1SZ 147456              // 2mb*18s*4mt*2hl*512
#define WP2OFF (WP1OFF + WP1SZ)
#define WP2SZ 442368              // 2mb*27s*8mt*2hl*512

__device__ __forceinline__ float sigm(float x) { return 1.0f / (1.0f + __expf(-x)); }
__device__ __forceinline__ ushort_t f2u(f16 v) { return __builtin_bit_cast(ushort_t, v); }
__device__ __forceinline__ f16x8 u2f(uint4 v) { return __builtin_bit_cast(f16x8, v); }

// ---- init: pack weights into fragment order, pose=fc_b, stage x[0] ----
__global__ __launch_bounds__(256) void pack_kernel(const float* __restrict__ w1,
                                                   const float* __restrict__ w2,
                                                   const float* __restrict__ fcb,
                                                   const float* __restrict__ x0,
                                                   float* __restrict__ pose,
                                                   ushort_t* __restrict__ wp1,
                                                   ushort_t* __restrict__ wp2,
                                                   ushort_t* __restrict__ in1hi0,
                                                   ushort_t* __restrict__ in1lo0) {
  int i = blockIdx.x * 256 + threadIdx.x;
  if (i < 55296) {  // wp2: thread per (f, hl, lane), 8 elems each
    int lane = i & 63;
    int r0 = i >> 6;        // [0, 864)
    int hl = r0 & 1;
    int f = r0 >> 1;        // [0, 432) = (mb*27+s)*8+mt
    int mt = f & 7;
    int sm = f >> 3;        // [0,54)
    int s = sm % 27, mb = sm / 27;
    int m = mt * 16 + (lane & 15);
    int rg = mb * 128 + m;
    int h = rg >> 2, G = rg & 3;
    int orow = G * 64 + h;
    int tap = s / 3, cb = (s % 3) * 32;
    int cq = cb + (lane >> 4) * 8;
    for (int j = 0; j < 8; ++j) {
      float v = w2[(orow * 96 + cq + j) * 9 + tap];
      f16 vh = (f16)v;
      f16 vl = (f16)(v - (float)vh);
      wp2[(f * 2 + hl) * 512 + lane * 8 + j] = f2u(hl ? vl : vh);
    }
    return;
  }
  i -= 55296;
  if (i < 18432) {  // wp1
    int lane = i & 63;
    int r0 = i >> 6;        // [0,288)
    int hl = r0 & 1;
    int f = r0 >> 1;        // [0,144) = (mb*18+s)*4+mt
    int mt = f & 3;
    int sm = f >> 2;        // [0,36)
    int s = sm % 18, mb = sm / 18;
    int m = mt * 16 + (lane & 15);
    int rg = mb * 64 + m;
    int h = rg >> 2, G = rg & 3;
    int orow = G * 32 + h;
    int tap = s >> 1, cb = (s & 1) * 32;
    int cq = cb + (lane >> 4) * 8;
    for (int j = 0; j < 8; ++j) {
      int c = cq + j;
      float v = (c < 35) ? w1[(orow * 35 + c) * 9 + tap] : 0.f;
      f16 vh = (f16)v;
      f16 vl = (f16)(v - (float)vh);
      wp1[(f * 2 + hl) * 512 + lane * 8 + j] = f2u(hl ? vl : vh);
    }
    return;
  }
  i -= 18432;
  if (i < 768) { pose[i] = fcb[i % 6]; return; }
  i -= 768;
  if (i < 12288) {  // x[0] -> in1[0] c0-2
    int c = i >> 12, pix = i & 4095;
    int y = pix >> 6, x = pix & 63;
    float v = x0[i];
    f16 vh = (f16)v;
    f16 vl = (f16)(v - (float)vh);
    int pidx = ((y + 1) * 66 + (x + 1)) * 48 + c;
    in1hi0[pidx] = f2u(vh);
    in1lo0[pidx] = f2u(vl);
  }
}

// ---- one ConvLSTM step for one layer ----
// grid 256 = 2 M-blocks x 128 pixel tiles (4y x 8x); block 256 = 4 waves.
template <int LAYER>
__global__ __launch_bounds__(256) void conv_step(
    const ushort_t* __restrict__ bhi, const ushort_t* __restrict__ blo,  // input buffer
    const ushort_t* __restrict__ wp, const float* __restrict__ bias,
    float* __restrict__ cst, float* __restrict__ hout,              // fp32 c (in-place), h
    ushort_t* __restrict__ d1hi, ushort_t* __restrict__ d1lo,       // primary padded dest
    ushort_t* __restrict__ d2hi, ushort_t* __restrict__ d2lo,       // secondary (L1 only)
    const float* __restrict__ fcw, float* __restrict__ pose_t,      // L2 only
    const float* __restrict__ xn,                                   // L2 only: x[t+1]
    ushort_t* __restrict__ xdhi, ushort_t* __restrict__ xdlo) {     // L2 only: in1 next
  constexpr int C = (LAYER == 1) ? 48 : 96;     // global c-stride
  constexpr int CS = (LAYER == 1) ? 72 : 104;   // LDS c-stride (bank-conflict pad)
  constexpr int NC32 = (LAYER == 1) ? 2 : 3;    // 32-channel chunks
  constexpr int NS = 9 * NC32;                  // k32 steps
  constexpr int MT = (LAYER == 1) ? 4 : 8;      // 16-row m-tiles per block
  constexpr int MTPW = (LAYER == 1) ? 1 : 2;    // m-tiles per wave
  constexpr int ROWS = MT * 16;
  constexpr int H = (LAYER == 1) ? 32 : 64;
  constexpr int ZS = 33;                        // z LDS stride (pad)
  constexpr int D1S = (LAYER == 1) ? 48 : 96;
  constexpr int D1O = (LAYER == 1) ? 3 : 32;

  __shared__ __align__(16) ushort_t Bh[60 * CS];
  __shared__ __align__(16) ushort_t Bl[60 * CS];
  __shared__ float zs[ROWS * ZS];
  __shared__ float red[4][6];

  const int tid = threadIdx.x;
  const int lane = tid & 63;
  const int w = tid >> 6;
  const int mb = blockIdx.x & 1;
  const int ntile = blockIdx.x >> 1;
  const int Y0 = (ntile >> 3) * 4;
  const int X0 = (ntile & 7) * 8;

  // ---- stage halo slab [6y][10x][C] into LDS (already-split f16) ----
  if (LAYER == 2) {
    for (int i = tid; i < 720; i += 256) {
      int hy = i / 120, rem = i % 120;
      int hx = rem / 12, c8 = (rem % 12) * 8;
      int src = ((Y0 + hy) * 66 + X0 + hx) * 96 + c8;
      int dst = (hy * 10 + hx) * CS + c8;
      *(uint4*)(&Bh[dst]) = *(const uint4*)(&bhi[src]);
      *(uint4*)(&Bl[dst]) = *(const uint4*)(&blo[src]);
    }
  } else {
    for (int i = tid; i < 360; i += 256) {
      int hy = i / 60, rem = i % 60;
      int hx = rem / 6, c8 = (rem % 6) * 8;
      int src = ((Y0 + hy) * 66 + X0 + hx) * 48 + c8;
      int dst = (hy * 10 + hx) * CS + c8;
      *(uint4*)(&Bh[dst]) = *(const uint4*)(&bhi[src]);
      *(uint4*)(&Bl[dst]) = *(const uint4*)(&blo[src]);
    }
    for (int i = tid; i < 120; i += 256) {  // zero-pad c 48..63 (read by frags)
      int hp = i >> 1;
      int dst = hp * CS + 48 + (i & 1) * 8;
      *(uint4*)(&Bh[dst]) = uint4{0, 0, 0, 0};
      *(uint4*)(&Bl[dst]) = uint4{0, 0, 0, 0};
    }
  }
  __syncthreads();

  // ---- K-loop: A frags from global (packed, prefetched), B frags from LDS ----
  const int n = lane & 15;
  const int q = lane >> 4;
  const int py = n >> 3, px = n & 7;

  f32x4 acc[MTPW][2];
#pragma unroll
  for (int m = 0; m < MTPW; ++m)
#pragma unroll
    for (int nt = 0; nt < 2; ++nt) acc[m][nt] = f32x4{0.f, 0.f, 0.f, 0.f};

  // per-wave A pointers, advance MT frags per k-step
  const ushort_t* aptr[MTPW];
#pragma unroll
  for (int m = 0; m < MTPW; ++m) {
    int f = (mb * NS + 0) * MT + (w * MTPW + m);
    aptr[m] = wp + f * 1024 + lane * 8;  // (f*2+0)*512
  }
  uint4 Abuf[2][MTPW][2];
#pragma unroll
  for (int m = 0; m < MTPW; ++m) {
    Abuf[0][m][0] = *(const uint4*)(aptr[m]);
    Abuf[0][m][1] = *(const uint4*)(aptr[m] + 512);
  }

  int s = 0;
  for (int tap = 0; tap < 9; ++tap) {
    int ty = tap / 3, tx = tap % 3;
    for (int cc = 0; cc < NC32; ++cc, ++s) {
      // prefetch next k-step's A frags
      if (s + 1 < NS) {
#pragma unroll
        for (int m = 0; m < MTPW; ++m) {
          const ushort_t* p = aptr[m] + (size_t)(s + 1) * MT * 1024;
          Abuf[(s + 1) & 1][m][0] = *(const uint4*)(p);
          Abuf[(s + 1) & 1][m][1] = *(const uint4*)(p + 512);
        }
      }
      int coff = cc * 32 + q * 8;
      f16x8 bfh[2], bfl[2];
#pragma unroll
      for (int nt = 0; nt < 2; ++nt) {
        int hp = (py + nt * 2 + ty) * 10 + (px + tx);
        int a = hp * CS + coff;
        bfh[nt] = u2f(*(const uint4*)(&Bh[a]));
        bfl[nt] = u2f(*(const uint4*)(&Bl[a]));
      }
#pragma unroll
      for (int m = 0; m < MTPW; ++m) {
        f16x8 ah = u2f(Abuf[s & 1][m][0]);
        f16x8 al = u2f(Abuf[s & 1][m][1]);
#pragma unroll
        for (int nt = 0; nt < 2; ++nt) {
          acc[m][nt] = __builtin_amdgcn_mfma_f32_16x16x32_f16(ah, bfh[nt], acc[m][nt], 0, 0, 0);
          acc[m][nt] = __builtin_amdgcn_mfma_f32_16x16x32_f16(ah, bfl[nt], acc[m][nt], 0, 0, 0);
          acc[m][nt] = __builtin_amdgcn_mfma_f32_16x16x32_f16(al, bfh[nt], acc[m][nt], 0, 0, 0);
        }
      }
    }
  }

  // ---- z exchange through LDS ----
#pragma unroll
  for (int m = 0; m < MTPW; ++m) {
    int mt = w * MTPW + m;
#pragma unroll
    for (int nt = 0; nt < 2; ++nt)
#pragma unroll
      for (int i = 0; i < 4; ++i) zs[(mt * 16 + q * 4 + i) * ZS + nt * 16 + n] = acc[m][nt][i];
  }
  __syncthreads();

  // ---- LSTM cell + state writes (+ FC fuse for L2) ----
  constexpr int NCELL = (MT * 4 * 32) / 256;  // cells per thread (L2: 4, L1: 2)
  float p6[6] = {0, 0, 0, 0, 0, 0};
#pragma unroll
  for (int i = 0; i < NCELL; ++i) {
    int idx = i * 256 + tid;
    int ch = idx >> 5, pI = idx & 31;
    float zi = zs[(ch * 4 + 0) * ZS + pI];
    float zf = zs[(ch * 4 + 1) * ZS + pI];
    float zo = zs[(ch * 4 + 2) * ZS + pI];
    float zg = zs[(ch * 4 + 3) * ZS + pI];
    int hg = mb * (MT * 4) + ch;
    zi += bias[0 * H + hg];
    zf += bias[1 * H + hg];
    zo += bias[2 * H + hg];
    zg += bias[3 * H + hg];
    int y = Y0 + (pI >> 3), x = X0 + (pI & 7);
    int cidx = hg * 4096 + y * 64 + x;
    float cold = cst[cidx];
    float cn = sigm(zf) * cold + sigm(zi) * tanhf(zg);
    float hn = sigm(zo) * tanhf(cn);
    cst[cidx] = cn;
    hout[cidx] = hn;
    f16 hh = (f16)hn;
    f16 hl = (f16)(hn - (float)hh);
    int pidx = (y + 1) * 66 + (x + 1);
    d1hi[pidx * D1S + D1O + hg] = f2u(hh);
    d1lo[pidx * D1S + D1O + hg] = f2u(hl);
    if (LAYER == 1) {
      d2hi[pidx * 96 + hg] = f2u(hh);
      d2lo[pidx * 96 + hg] = f2u(hl);
    } else {
#pragma unroll
      for (int j = 0; j < 6; ++j) p6[j] += hn * fcw[j * 262144 + cidx];
    }
  }

  if (LAYER == 2) {
#pragma unroll
    for (int j = 0; j < 6; ++j)
#pragma unroll
      for (int off = 32; off > 0; off >>= 1) p6[j] += __shfl_xor(p6[j], off, 64);
    if (lane == 0)
#pragma unroll
      for (int j = 0; j < 6; ++j) red[w][j] = p6[j];
    __syncthreads();
    if (tid < 6) atomicAdd(pose_t + tid, red[0][tid] + red[1][tid] + red[2][tid] + red[3][tid]);
    // stage x[t+1] into in1 next-parity (c0-2)
    if (mb == 0 && tid < 32) {
      int y = Y0 + (tid >> 3), x = X0 + (tid & 7);
      int pidx = (y + 1) * 66 + (x + 1);
#pragma unroll
      for (int c = 0; c < 3; ++c) {
        float v = xn[c * 4096 + y * 64 + x];
        f16 vh = (f16)v;
        f16 vl = (f16)(v - (float)vh);
        xdhi[pidx * 48 + c] = f2u(vh);
        xdlo[pidx * 48 + c] = f2u(vl);
      }
    }
  }
}

extern "C" void kernel_launch(void* const* d_in, const int* in_sizes, int n_in, void* d_out,
                              int out_size, void* d_ws, size_t ws_size, hipStream_t stream) {
  const float* input = (const float*)d_in[0];
  const float* w1 = (const float*)d_in[1];
  const float* b1 = (const float*)d_in[2];
  const float* w2 = (const float*)d_in[3];
  const float* b2 = (const float*)d_in[4];
  const float* fcw = (const float*)d_in[5];
  const float* fcb = (const float*)d_in[6];

  float* out = (float*)d_out;
  float* pose = out;
  float* h1o = out + 768;
  float* c1o = h1o + 131072;
  float* h2o = c1o + 131072;
  float* c2o = h2o + 262144;

  ushort_t* ws = (ushort_t*)d_ws;
  ushort_t* in1hi[2] = {ws, ws + IN1SZ};
  ushort_t* in1lo[2] = {ws + 2 * IN1SZ, ws + 3 * IN1SZ};
  ushort_t* i2base = ws + 4 * IN1SZ;
  ushort_t* in2hi[2] = {i2base, i2base + IN2SZ};
  ushort_t* in2lo[2] = {i2base + 2 * IN2SZ, i2base + 3 * IN2SZ};
  ushort_t* wp1 = ws + WP1OFF;
  ushort_t* wp2 = ws + WP2OFF;

  // zero state buffers (t=0 h-states + padded borders + c-pads), c/h fp32 states
  hipMemsetAsync(ws, 0, (size_t)WP1OFF * 2, stream);
  hipMemsetAsync(out + 768, 0, (size_t)786432 * 4, stream);
  pack_kernel<<<339, 256, 0, stream>>>(w1, w2, fcb, input, pose, wp1, wp2, in1hi[0], in1lo[0]);

  for (int t = 0; t < 128; ++t) {
    int p = t & 1, pn = p ^ 1;
    conv_step<1><<<256, 256, 0, stream>>>(in1hi[p], in1lo[p], wp1, b1, c1o, h1o,
                                          in1hi[pn], in1lo[pn],  // h1 -> in1 next @c3
                                          in2hi[p], in2lo[p],    // h1 -> in2 cur  @c0
                                          nullptr, nullptr, nullptr, nullptr, nullptr);
    int tn = (t + 1 < 128) ? t + 1 : 127;
    conv_step<2><<<256, 256, 0, stream>>>(in2hi[p], in2lo[p], wp2, b2, c2o, h2o,
                                          in2hi[pn], in2lo[pn],  // h2 -> in2 next @c32
                                          nullptr, nullptr,
                                          fcw, pose + t * 6,
                                          input + (size_t)tn * 12288, in1hi[pn], in1lo[pn]);
  }
}